// Round 8
// baseline (191.405 us; speedup 1.0000x reference)
//
#include <hip/hip_runtime.h>
#include <hip/hip_bf16.h>
#include <stdint.h>

#define NB   8
#define NSEQ 4096
#define DIN  128
#define DK   64
#define DVV  128

typedef __bf16 bf16x8 __attribute__((ext_vector_type(8)));
typedef float f32x4 __attribute__((ext_vector_type(4)));
typedef unsigned int u32x4v __attribute__((ext_vector_type(4)));
typedef unsigned short u16;
typedef unsigned int u32;

__device__ __forceinline__ u32 cvt_pk_bf16(float lo, float hi) {
  u32 r;
  asm("v_cvt_pk_bf16_f32 %0, %1, %2" : "=v"(r) : "v"(lo), "v"(hi));
  return r;
}

// ---------------- projection via MFMA, single-pass x (unchanged, ~8us) ----------
__global__ __launch_bounds__(256) void proj(
    const float* __restrict__ x, const float* __restrict__ Wq,
    const float* __restrict__ Wk, const float* __restrict__ Wv,
    u16* __restrict__ Qb, u16* __restrict__ Kb, u16* __restrict__ Vtb) {
  __shared__ alignas(16) u16 xs[64 * 128];
  const int tid = threadIdx.x;
  const int w = tid >> 6, l = tid & 63;
  const int lg = l >> 4, li = l & 15;
  const int b = blockIdx.x & 7;
  const int n0 = (blockIdx.x >> 3) << 6;

  {
    const float* xp = x + ((size_t)b * DIN + w * 32) * NSEQ + n0 + l;
    #pragma unroll
    for (int cc = 0; cc < 4; ++cc) {
      const int c = w * 4 + cc;
      u32 pk[4];
      #pragma unroll
      for (int jj = 0; jj < 4; ++jj) {
        const float f0 = xp[(size_t)(cc * 8 + 2 * jj) * NSEQ];
        const float f1 = xp[(size_t)(cc * 8 + 2 * jj + 1) * NSEQ];
        pk[jj] = cvt_pk_bf16(f0, f1);
      }
      *(uint4*)&xs[l * 128 + ((c ^ (l & 15)) * 8)] = *(uint4*)pk;
    }
  }

  const float* W;
  float scale = 1.0f;
  if (w == 0)      { W = Wq; scale = 0.180336880111120429f; }  // log2e/8
  else if (w == 1) { W = Wk; }
  else if (w == 2) { W = Wv; }
  else             { W = Wv + 64 * DIN; }

  bf16x8 wf[4][4];
  #pragma unroll
  for (int ct = 0; ct < 4; ++ct) {
    const float* wr = W + (ct * 16 + li) * DIN + lg * 8;
    #pragma unroll
    for (int ks = 0; ks < 4; ++ks) {
      const float4 f0 = *(const float4*)(wr + 32 * ks);
      const float4 f1 = *(const float4*)(wr + 32 * ks + 4);
      u32x4v pk;
      pk[0] = cvt_pk_bf16(f0.x * scale, f0.y * scale);
      pk[1] = cvt_pk_bf16(f0.z * scale, f0.w * scale);
      pk[2] = cvt_pk_bf16(f1.x * scale, f1.y * scale);
      pk[3] = cvt_pk_bf16(f1.z * scale, f1.w * scale);
      wf[ct][ks] = __builtin_bit_cast(bf16x8, pk);
    }
  }

  __syncthreads();

  const f32x4 fz = {0.f, 0.f, 0.f, 0.f};
  #pragma unroll
  for (int nt = 0; nt < 4; ++nt) {
    const int n16 = n0 + nt * 16;
    bf16x8 xf[4];
    #pragma unroll
    for (int ks = 0; ks < 4; ++ks)
      xf[ks] = *(const bf16x8*)&xs[(nt * 16 + li) * 128 + (((lg + 4 * ks) ^ li) * 8)];
    #pragma unroll
    for (int ct = 0; ct < 4; ++ct) {
      f32x4 acc = fz;
      if (w < 2) {
        #pragma unroll
        for (int ks = 0; ks < 4; ++ks)
          acc = __builtin_amdgcn_mfma_f32_16x16x32_bf16(xf[ks], wf[ct][ks], acc, 0, 0, 0);
        u16* ob = (w == 0 ? Qb : Kb) + (size_t)b * NSEQ * DK;
        #pragma unroll
        for (int r = 0; r < 4; ++r)
          ob[(size_t)(n16 + lg * 4 + r) * DK + ct * 16 + li] =
              (u16)cvt_pk_bf16(acc[r], acc[r]);
      } else {
        #pragma unroll
        for (int ks = 0; ks < 4; ++ks)
          acc = __builtin_amdgcn_mfma_f32_16x16x32_bf16(wf[ct][ks], xf[ks], acc, 0, 0, 0);
        const int chb = (w == 3 ? 64 : 0) + ct * 16 + lg * 4;
        #pragma unroll
        for (int r = 0; r < 4; ++r)
          Vtb[((size_t)b * DVV + chb + r) * NSEQ + n16 + li] =
              (u16)cvt_pk_bf16(acc[r], acc[r]);
      }
    }
  }
}

// ---------------- fused flash attention: barrier-free async waves ----------------
// 512 blocks (b(8)=XCD x qg(64)) x 256 threads = 4 waves = 2 q-waves(wp) x 2
// kv-groups(g). NO LDS, NO __syncthreads in the main loop: each wave reads its
// K AND V fragments directly from the XCD-local L2 (batch K+V = 1.5MB < 4MB).
// KVBLK=32; wave g handles tiles t = 2i+g (64 iters). Twin waves (wp=0/1, same
// g) issue identical K/V addresses ~in-sync -> L1 absorbs the second stream.
// K row-permutation T(jt*16+lg*4+r) = lg*8+4jt+r folded into the K pointer so
// each lane's 8 P values per half ARE its PV B-fragment (in-lane cvt_pk pack).
// Fixed-max softmax (exp2 domain, shift-invariant). K double-buffered one iter
// ahead in regs; V issued at iter top, consumed at PV (~300cyc later).
// Merge: single barrier at the end; g=1 partials combined by g=0 via LDS.
__global__ __launch_bounds__(256, 2) void attn(
    const u16* __restrict__ Qb, const u16* __restrict__ Kb,
    const u16* __restrict__ Vtb, const float* __restrict__ x,
    float* __restrict__ out) {
  __shared__ alignas(16) char lds[34816];  // 2 x [128][33] f32 pairO + 2 x 512B stats
  const int tid = threadIdx.x;
  const int w = tid >> 6, l = tid & 63;
  const int lg = l >> 4, li = l & 15;
  const int wp = w >> 1, g = w & 1;
  const int b = blockIdx.x & 7;
  const int n0 = (blockIdx.x >> 3) << 6;    // 64 q per block
  const int qbase = n0 + wp * 32;

  // Q B-fragments: qf[h][kc]: col q = qbase+16h+li, d-chunk kc*32 + lg*8
  bf16x8 qf[2][2];
  #pragma unroll
  for (int h = 0; h < 2; ++h) {
    const u16* qp = Qb + ((size_t)(b * NSEQ + qbase + h * 16 + li) * DK + lg * 8);
    qf[h][0] = *(const bf16x8*)qp;
    qf[h][1] = *(const bf16x8*)(qp + 32);
  }

  const f32x4 fzero = {0.f, 0.f, 0.f, 0.f};
  f32x4 oacc[2][8];
  #pragma unroll
  for (int h = 0; h < 2; ++h)
    #pragma unroll
    for (int dt = 0; dt < 8; ++dt) oacc[h][dt] = fzero;
  float lrow[2] = {0.f, 0.f};

  // K direct: staged A-row (jt,li) holds actual kv row 8*(li>>2)+4*jt+(li&3)
  // within the tile (permutation T); frag (jt,kc) at kbase + (t*32+4jt)*DK + kc*32.
  const u16* kbase = Kb + ((size_t)b * NSEQ + 8 * (li >> 2) + (li & 3)) * DK + lg * 8;
  // V direct (no permutation): vf[dt] lane (lg,li): V^T[dt*16+li][t*32 + lg*8 + j]
  const u16* vbase = Vtb + ((size_t)b * DVV + li) * NSEQ + lg * 8;

  bf16x8 kfa[2][2], kfb[2][2];
#define KLOAD(KF, T) do {                                                     \
    const u16* kp_ = kbase + (size_t)(T) * 32 * DK;                           \
    _Pragma("unroll") for (int jt = 0; jt < 2; ++jt)                          \
      _Pragma("unroll") for (int kc = 0; kc < 2; ++kc)                        \
        KF[jt][kc] = *(const bf16x8*)(kp_ + 4 * jt * DK + kc * 32);           \
  } while (0)

  KLOAD(kfa, g);   // tile for i=0

#define BODY(KC, KN, I) do {                                                  \
    const int t_ = g + 2 * (I);                                               \
    /* V loads issued early, consumed at PV */                                \
    bf16x8 vf[8];                                                             \
    _Pragma("unroll") for (int dt = 0; dt < 8; ++dt)                          \
      vf[dt] = *(const bf16x8*)(vbase + (size_t)dt * 16 * NSEQ + t_ * 32);    \
    /* S^T = K Q^T from registers */                                          \
    f32x4 s4[2][2];                                                           \
    __builtin_amdgcn_s_setprio(1);                                            \
    _Pragma("unroll") for (int jt = 0; jt < 2; ++jt)                          \
      _Pragma("unroll") for (int h = 0; h < 2; ++h) {                         \
        s4[h][jt] = __builtin_amdgcn_mfma_f32_16x16x32_bf16(                  \
            KC[jt][0], qf[h][0], fzero, 0, 0, 0);                             \
        s4[h][jt] = __builtin_amdgcn_mfma_f32_16x16x32_bf16(                  \
            KC[jt][1], qf[h][1], s4[h][jt], 0, 0, 0);                         \
      }                                                                       \
    __builtin_amdgcn_s_setprio(0);                                            \
    /* K prefetch for next iter's tile */                                     \
    if ((I) < 63) KLOAD(KN, t_ + 2);                                          \
    /* fixed-max softmax + in-lane P pack (B-slot j = 4*jt + r) */            \
    bf16x8 pf[2];                                                             \
    _Pragma("unroll") for (int h = 0; h < 2; ++h) {                           \
      float p_[8];                                                            \
      _Pragma("unroll") for (int jt = 0; jt < 2; ++jt)                        \
        _Pragma("unroll") for (int r = 0; r < 4; ++r)                         \
          p_[jt * 4 + r] = __builtin_amdgcn_exp2f(s4[h][jt][r]);              \
      lrow[h] += ((p_[0] + p_[1]) + (p_[2] + p_[3]))                          \
               + ((p_[4] + p_[5]) + (p_[6] + p_[7]));                         \
      u32x4v pk_;                                                             \
      pk_[0] = cvt_pk_bf16(p_[0], p_[1]);                                     \
      pk_[1] = cvt_pk_bf16(p_[2], p_[3]);                                     \
      pk_[2] = cvt_pk_bf16(p_[4], p_[5]);                                     \
      pk_[3] = cvt_pk_bf16(p_[6], p_[7]);                                     \
      pf[h] = __builtin_bit_cast(bf16x8, pk_);                                \
    }                                                                         \
    /* O^T += V^T P (V frags shared across halves) */                         \
    __builtin_amdgcn_s_setprio(1);                                            \
    _Pragma("unroll") for (int dt = 0; dt < 8; ++dt)                          \
      _Pragma("unroll") for (int h = 0; h < 2; ++h)                           \
        oacc[h][dt] = __builtin_amdgcn_mfma_f32_16x16x32_bf16(                \
            vf[dt], pf[h], oacc[h][dt], 0, 0, 0);                             \
    __builtin_amdgcn_s_setprio(0);                                            \
  } while (0)

  #pragma unroll 1
  for (int ii = 0; ii < 32; ++ii) {
    BODY(kfa, kfb, 2 * ii);
    BODY(kfb, kfa, 2 * ii + 1);
  }

  // ---- merge epilogue (the only synchronization) ----
  float* const pairO = (float*)(lds + wp * 16896);        // [128 dv][33] f32 padded
  float* const stats = (float*)(lds + 33792 + wp * 512);  // [2 h][64 l] floats
  if (g == 1) {
    #pragma unroll
    for (int h = 0; h < 2; ++h)
      stats[h * 64 + l] = lrow[h];
    #pragma unroll
    for (int h = 0; h < 2; ++h)
      #pragma unroll
      for (int dt = 0; dt < 8; ++dt)
        #pragma unroll
        for (int r = 0; r < 4; ++r)
          pairO[(dt * 16 + lg * 4 + r) * 33 + h * 16 + li] = oacc[h][dt][r];
  }
  __syncthreads();
  if (g == 0) {
    #pragma unroll
    for (int h = 0; h < 2; ++h) {
      float ls = lrow[h] + stats[h * 64 + l];
      ls += __shfl_xor(ls, 16, 64);
      ls += __shfl_xor(ls, 32, 64);
      const float rl = 1.0f / ls;
      #pragma unroll
      for (int dt = 0; dt < 8; ++dt) {
        #pragma unroll
        for (int r = 0; r < 4; ++r) {
          const int dv = dt * 16 + lg * 4 + r;
          const float oB = pairO[dv * 33 + h * 16 + li];
          const size_t idx = ((size_t)b * DVV + dv) * NSEQ + qbase + h * 16 + li;
          out[idx] = (oacc[h][dt][r] + oB) * rl + x[idx];
        }
      }
    }
  }
#undef KLOAD
#undef BODY
}

extern "C" void kernel_launch(void* const* d_in, const int* in_sizes, int n_in,
                              void* d_out, int out_size, void* d_ws, size_t ws_size,
                              hipStream_t stream) {
  const float* x  = (const float*)d_in[0];
  const float* Wq = (const float*)d_in[1];
  const float* Wk = (const float*)d_in[2];
  const float* Wv = (const float*)d_in[3];
  float* out = (float*)d_out;

  u16* qws = (u16*)d_ws;                                   // [8][4096][64]
  u16* kws = qws + (size_t)NB * NSEQ * DK;                 // [8][4096][64]
  u16* vws = kws + (size_t)NB * NSEQ * DK;                 // [8][128][4096]

  proj<<<512, 256, 0, stream>>>(x, Wq, Wk, Wv, qws, kws, vws);
  attn<<<512, 256, 0, stream>>>(qws, kws, vws, x, out);
}

// Round 10
// 181.984 us; speedup vs baseline: 1.0518x; 1.0518x over previous
//
#include <hip/hip_runtime.h>
#include <hip/hip_bf16.h>
#include <stdint.h>

#define NB   8
#define NSEQ 4096
#define DIN  128
#define DK   64
#define DVV  128

typedef __bf16 bf16x8 __attribute__((ext_vector_type(8)));
typedef float f32x4 __attribute__((ext_vector_type(4)));
typedef unsigned int u32x4v __attribute__((ext_vector_type(4)));
typedef unsigned short u16;
typedef unsigned int u32;

__device__ __forceinline__ u32 cvt_pk_bf16(float lo, float hi) {
  u32 r;
  asm("v_cvt_pk_bf16_f32 %0, %1, %2" : "=v"(r) : "v"(lo), "v"(hi));
  return r;
}

// ---------------- projection via MFMA, single-pass x (unchanged, ~8us) ----------
__global__ __launch_bounds__(256) void proj(
    const float* __restrict__ x, const float* __restrict__ Wq,
    const float* __restrict__ Wk, const float* __restrict__ Wv,
    u16* __restrict__ Qb, u16* __restrict__ Kb, u16* __restrict__ Vtb) {
  __shared__ alignas(16) u16 xs[64 * 128];
  const int tid = threadIdx.x;
  const int w = tid >> 6, l = tid & 63;
  const int lg = l >> 4, li = l & 15;
  const int b = blockIdx.x & 7;
  const int n0 = (blockIdx.x >> 3) << 6;

  {
    const float* xp = x + ((size_t)b * DIN + w * 32) * NSEQ + n0 + l;
    #pragma unroll
    for (int cc = 0; cc < 4; ++cc) {
      const int c = w * 4 + cc;
      u32 pk[4];
      #pragma unroll
      for (int jj = 0; jj < 4; ++jj) {
        const float f0 = xp[(size_t)(cc * 8 + 2 * jj) * NSEQ];
        const float f1 = xp[(size_t)(cc * 8 + 2 * jj + 1) * NSEQ];
        pk[jj] = cvt_pk_bf16(f0, f1);
      }
      *(uint4*)&xs[l * 128 + ((c ^ (l & 15)) * 8)] = *(uint4*)pk;
    }
  }

  const float* W;
  float scale = 1.0f;
  if (w == 0)      { W = Wq; scale = 0.180336880111120429f; }  // log2e/8
  else if (w == 1) { W = Wk; }
  else if (w == 2) { W = Wv; }
  else             { W = Wv + 64 * DIN; }

  bf16x8 wf[4][4];
  #pragma unroll
  for (int ct = 0; ct < 4; ++ct) {
    const float* wr = W + (ct * 16 + li) * DIN + lg * 8;
    #pragma unroll
    for (int ks = 0; ks < 4; ++ks) {
      const float4 f0 = *(const float4*)(wr + 32 * ks);
      const float4 f1 = *(const float4*)(wr + 32 * ks + 4);
      u32x4v pk;
      pk[0] = cvt_pk_bf16(f0.x * scale, f0.y * scale);
      pk[1] = cvt_pk_bf16(f0.z * scale, f0.w * scale);
      pk[2] = cvt_pk_bf16(f1.x * scale, f1.y * scale);
      pk[3] = cvt_pk_bf16(f1.z * scale, f1.w * scale);
      wf[ct][ks] = __builtin_bit_cast(bf16x8, pk);
    }
  }

  __syncthreads();

  const f32x4 fz = {0.f, 0.f, 0.f, 0.f};
  #pragma unroll
  for (int nt = 0; nt < 4; ++nt) {
    const int n16 = n0 + nt * 16;
    bf16x8 xf[4];
    #pragma unroll
    for (int ks = 0; ks < 4; ++ks)
      xf[ks] = *(const bf16x8*)&xs[(nt * 16 + li) * 128 + (((lg + 4 * ks) ^ li) * 8)];
    #pragma unroll
    for (int ct = 0; ct < 4; ++ct) {
      f32x4 acc = fz;
      if (w < 2) {
        #pragma unroll
        for (int ks = 0; ks < 4; ++ks)
          acc = __builtin_amdgcn_mfma_f32_16x16x32_bf16(xf[ks], wf[ct][ks], acc, 0, 0, 0);
        u16* ob = (w == 0 ? Qb : Kb) + (size_t)b * NSEQ * DK;
        #pragma unroll
        for (int r = 0; r < 4; ++r)
          ob[(size_t)(n16 + lg * 4 + r) * DK + ct * 16 + li] =
              (u16)cvt_pk_bf16(acc[r], acc[r]);
      } else {
        #pragma unroll
        for (int ks = 0; ks < 4; ++ks)
          acc = __builtin_amdgcn_mfma_f32_16x16x32_bf16(wf[ct][ks], xf[ks], acc, 0, 0, 0);
        const int chb = (w == 3 ? 64 : 0) + ct * 16 + lg * 4;
        #pragma unroll
        for (int r = 0; r < 4; ++r)
          Vtb[((size_t)b * DVV + chb + r) * NSEQ + n16 + li] =
              (u16)cvt_pk_bf16(acc[r], acc[r]);
      }
    }
  }
}

// ------- fused flash attention: kv-split-4, Wq=64, private-LDS V, NO main-loop barrier -------
// 512 blocks (b(8)=XCD x qg(64)) x 4 waves. Wave w owns kv quarter [w*1024,(w+1)*1024),
// KVBLK=32, and ALL 64 q rows of the block (Wq=64: 4 q-halves). Quarters are disjoint
// so each V/K byte is still read from L2 exactly once per block.
// V: coalesced global loads -> regs -> private LDS tile (2 x 8KB double buffer per
// wave, [128 dv][32 kv] row-major, 64B rows) -> contiguous b128 frag reads (2-way
// bank aliasing = free). Same-wave LDS ordering is automatic (lgkmcnt) -> NO
// __syncthreads in the main loop; per-wave stalls absorbed by 7 other waves/CU.
// K: register fragments gathered from L2, single-buffered, reloaded after QK.
// Fixed-max softmax (shift-invariant, exp2 domain). Epilogue: 4-partial merge tree.
__global__ __launch_bounds__(256, 2) void attn(
    const u16* __restrict__ Qb, const u16* __restrict__ Kb,
    const u16* __restrict__ Vtb, const float* __restrict__ x,
    float* __restrict__ out) {
  __shared__ alignas(16) char lds[69632];  // main 64KB; epi 2x33792 + 1KB stats
  const int tid = threadIdx.x;
  const int w = tid >> 6, l = tid & 63;
  const int lg = l >> 4, li = l & 15;
  const int b = blockIdx.x & 7;
  const int qbase = (blockIdx.x >> 3) << 6;

  // Q B-fragments: qf[h][kc]: col q = qbase+16h+li, d-chunk kc*32 + lg*8
  bf16x8 qf[4][2];
  #pragma unroll
  for (int h = 0; h < 4; ++h) {
    const u16* qp = Qb + ((size_t)(b * NSEQ + qbase + h * 16 + li) * DK + lg * 8);
    qf[h][0] = *(const bf16x8*)qp;
    qf[h][1] = *(const bf16x8*)(qp + 32);
  }

  const f32x4 fzero = {0.f, 0.f, 0.f, 0.f};
  f32x4 oacc[4][8];
  #pragma unroll
  for (int h = 0; h < 4; ++h)
    #pragma unroll
    for (int dt = 0; dt < 8; ++dt) oacc[h][dt] = fzero;
  float lrow[4] = {0.f, 0.f, 0.f, 0.f};

  // K gather base (row-permutation folded): A-row li of QK tile jt holds actual
  // kv row 8*(li>>2) + 4*jt + (li&3) within the 32-row tile.
  const u16* kbase = Kb + ((size_t)b * NSEQ + 8 * (li >> 2) + (li & 3)) * DK + lg * 8;
  // V stage source: lane l, slot s reads V^T[s*16 + (l>>2)][t*32 + (l&3)*8 ..+7]
  const u16* vsrc = Vtb + ((size_t)b * DVV + (l >> 2)) * NSEQ + (l & 3) * 8;
  char* const mybuf = lds + w * 16384;   // two private 8KB tiles

  bf16x8 kf[2][2];
  uint4 stg[8];
#define KLOAD(T) do {                                                         \
    const u16* kp_ = kbase + (size_t)(T) * 32 * DK;                           \
    _Pragma("unroll") for (int jt = 0; jt < 2; ++jt)                          \
      _Pragma("unroll") for (int kc = 0; kc < 2; ++kc)                        \
        kf[jt][kc] = *(const bf16x8*)(kp_ + jt * 4 * DK + kc * 32);           \
  } while (0)
#define LOADV(T) do {                                                         \
    _Pragma("unroll") for (int s = 0; s < 8; ++s)                             \
      stg[s] = *(const uint4*)(vsrc + (size_t)s * 16 * NSEQ + (size_t)(T) * 32); \
  } while (0)
#define WRITEV(B) do {                                                        \
    char* vb_ = mybuf + (B) * 8192;                                           \
    _Pragma("unroll") for (int s = 0; s < 8; ++s)                             \
      *(uint4*)(vb_ + (s * 64 + l) * 16) = stg[s];                            \
  } while (0)

  const int t0 = w * 32;                 // this wave's first kv tile
  KLOAD(t0);
  LOADV(t0);
  WRITEV(0);

  #pragma unroll 1
  for (int i = 0; i < 32; ++i) {
    const int t = t0 + i;
    const int cur = i & 1;
    if (i < 31) LOADV(t + 1);            // coalesced V loads for next tile

    // ---- S^T = K Q^T + fixed-max softmax + in-lane P pack, per q-half ----
    bf16x8 pf[4];
    __builtin_amdgcn_s_setprio(1);
    #pragma unroll
    for (int h = 0; h < 4; ++h) {
      f32x4 a0 = __builtin_amdgcn_mfma_f32_16x16x32_bf16(kf[0][0], qf[h][0], fzero, 0, 0, 0);
      a0 = __builtin_amdgcn_mfma_f32_16x16x32_bf16(kf[0][1], qf[h][1], a0, 0, 0, 0);
      f32x4 a1 = __builtin_amdgcn_mfma_f32_16x16x32_bf16(kf[1][0], qf[h][0], fzero, 0, 0, 0);
      a1 = __builtin_amdgcn_mfma_f32_16x16x32_bf16(kf[1][1], qf[h][1], a1, 0, 0, 0);
      float p0 = __builtin_amdgcn_exp2f(a0[0]);
      float p1 = __builtin_amdgcn_exp2f(a0[1]);
      float p2 = __builtin_amdgcn_exp2f(a0[2]);
      float p3 = __builtin_amdgcn_exp2f(a0[3]);
      float p4 = __builtin_amdgcn_exp2f(a1[0]);
      float p5 = __builtin_amdgcn_exp2f(a1[1]);
      float p6 = __builtin_amdgcn_exp2f(a1[2]);
      float p7 = __builtin_amdgcn_exp2f(a1[3]);
      lrow[h] += ((p0 + p1) + (p2 + p3)) + ((p4 + p5) + (p6 + p7));
      u32x4v pk;
      pk[0] = cvt_pk_bf16(p0, p1);
      pk[1] = cvt_pk_bf16(p2, p3);
      pk[2] = cvt_pk_bf16(p4, p5);
      pk[3] = cvt_pk_bf16(p6, p7);
      pf[h] = __builtin_bit_cast(bf16x8, pk);
    }
    __builtin_amdgcn_s_setprio(0);

    if (i < 31) KLOAD(t + 1);            // K gather for next tile (kf now dead)
    if (i < 31) WRITEV(cur ^ 1);         // stg -> other buf; frees stg before PV

    // ---- O^T += V^T P  (V frags from private LDS, shared across 4 halves) ----
    const char* vb = mybuf + cur * 8192;
    __builtin_amdgcn_s_setprio(1);
    #pragma unroll
    for (int dt = 0; dt < 8; ++dt) {
      const bf16x8 vf = *(const bf16x8*)(vb + dt * 1024 + li * 64 + lg * 16);
      #pragma unroll
      for (int h = 0; h < 4; ++h)
        oacc[h][dt] = __builtin_amdgcn_mfma_f32_16x16x32_bf16(vf, pf[h], oacc[h][dt], 0, 0, 0);
    }
    __builtin_amdgcn_s_setprio(0);
  }

  // ---- epilogue: 4-partial merge tree (the only barriers) ----
  #pragma unroll
  for (int h = 0; h < 4; ++h) {          // reduce l over lg groups
    lrow[h] += __shfl_xor(lrow[h], 16, 64);
    lrow[h] += __shfl_xor(lrow[h], 32, 64);
  }
  float* const bufA = (float*)lds;                 // [128 dv][66] f32
  float* const bufB = (float*)(lds + 33792);       // [128 dv][66] f32
  float* const stats = (float*)(lds + 67584);      // [4 w][4 h][16 li]
#define DUMP(DST) do {                                                        \
    _Pragma("unroll") for (int h = 0; h < 4; ++h)                             \
      _Pragma("unroll") for (int dt = 0; dt < 8; ++dt)                        \
        _Pragma("unroll") for (int r = 0; r < 4; ++r)                         \
          (DST)[(dt * 16 + lg * 4 + r) * 66 + h * 16 + li] = oacc[h][dt][r];  \
  } while (0)
#define ADDF(SRC) do {                                                        \
    _Pragma("unroll") for (int h = 0; h < 4; ++h)                             \
      _Pragma("unroll") for (int dt = 0; dt < 8; ++dt)                        \
        _Pragma("unroll") for (int r = 0; r < 4; ++r)                         \
          oacc[h][dt][r] += (SRC)[(dt * 16 + lg * 4 + r) * 66 + h * 16 + li]; \
  } while (0)
#define SAVESTATS(WI) do {                                                    \
    if (lg == 0) {                                                            \
      for (int h = 0; h < 4; ++h) stats[(WI) * 64 + h * 16 + li] = lrow[h];   \
    }                                                                         \
  } while (0)
  __syncthreads();                        // V bufs dead; epilogue regions live
  if (w == 1) { DUMP(bufA); SAVESTATS(1); }
  if (w == 3) { DUMP(bufB); SAVESTATS(3); }
  __syncthreads();
  if (w == 0) ADDF(bufA);
  if (w == 2) {
    ADDF(bufB);
    #pragma unroll
    for (int h = 0; h < 4; ++h) lrow[h] += stats[3 * 64 + h * 16 + li];
  }
  __syncthreads();
  if (w == 2) { DUMP(bufA); SAVESTATS(2); }
  __syncthreads();
  if (w == 0) {
    ADDF(bufA);
    #pragma unroll
    for (int h = 0; h < 4; ++h) {
      const float ls = lrow[h] + stats[1 * 64 + h * 16 + li] + stats[2 * 64 + h * 16 + li];
      const float rl = 1.0f / ls;
      #pragma unroll
      for (int dt = 0; dt < 8; ++dt) {
        #pragma unroll
        for (int r = 0; r < 4; ++r) {
          const int dv = dt * 16 + lg * 4 + r;
          const size_t idx = ((size_t)b * DVV + dv) * NSEQ + qbase + h * 16 + li;
          out[idx] = oacc[h][dt][r] * rl + x[idx];
        }
      }
    }
  }
#undef KLOAD
#undef LOADV
#undef WRITEV
#undef DUMP
#undef ADDF
#undef SAVESTATS
}

extern "C" void kernel_launch(void* const* d_in, const int* in_sizes, int n_in,
                              void* d_out, int out_size, void* d_ws, size_t ws_size,
                              hipStream_t stream) {
  const float* x  = (const float*)d_in[0];
  const float* Wq = (const float*)d_in[1];
  const float* Wk = (const float*)d_in[2];
  const float* Wv = (const float*)d_in[3];
  float* out = (float*)d_out;

  u16* qws = (u16*)d_ws;                                   // [8][4096][64]
  u16* kws = qws + (size_t)NB * NSEQ * DK;                 // [8][4096][64]
  u16* vws = kws + (size_t)NB * NSEQ * DK;                 // [8][128][4096]

  proj<<<512, 256, 0, stream>>>(x, Wq, Wk, Wv, qws, kws, vws);
  attn<<<512, 256, 0, stream>>>(qws, kws, vws, x, out);
}

// Round 11
// 83.345 us; speedup vs baseline: 2.2965x; 2.1835x over previous
//
#include <hip/hip_runtime.h>
#include <hip/hip_bf16.h>
#include <stdint.h>

#define NB   8
#define NSEQ 4096
#define DIN  128
#define DK   64
#define DVV  128

typedef __bf16 bf16x8 __attribute__((ext_vector_type(8)));
typedef float f32x4 __attribute__((ext_vector_type(4)));
typedef unsigned int u32x4v __attribute__((ext_vector_type(4)));
typedef unsigned short u16;
typedef unsigned int u32;

__device__ __forceinline__ u32 cvt_pk_bf16(float lo, float hi) {
  u32 r;
  asm("v_cvt_pk_bf16_f32 %0, %1, %2" : "=v"(r) : "v"(lo), "v"(hi));
  return r;
}

// async global->LDS, 16B/lane; LDS dest = wave-uniform base + lane*16 (HW rule)
#define GLDS16(G, L)                                                          \
  __builtin_amdgcn_global_load_lds(                                           \
      (__attribute__((address_space(1))) void*)(G),                           \
      (__attribute__((address_space(3))) void*)(L), 16, 0, 0)

// ---------------- projection via MFMA, single-pass x (unchanged, ~8us) ----------
__global__ __launch_bounds__(256) void proj(
    const float* __restrict__ x, const float* __restrict__ Wq,
    const float* __restrict__ Wk, const float* __restrict__ Wv,
    u16* __restrict__ Qb, u16* __restrict__ Kb, u16* __restrict__ Vtb) {
  __shared__ alignas(16) u16 xs[64 * 128];
  const int tid = threadIdx.x;
  const int w = tid >> 6, l = tid & 63;
  const int lg = l >> 4, li = l & 15;
  const int b = blockIdx.x & 7;
  const int n0 = (blockIdx.x >> 3) << 6;

  {
    const float* xp = x + ((size_t)b * DIN + w * 32) * NSEQ + n0 + l;
    #pragma unroll
    for (int cc = 0; cc < 4; ++cc) {
      const int c = w * 4 + cc;
      u32 pk[4];
      #pragma unroll
      for (int jj = 0; jj < 4; ++jj) {
        const float f0 = xp[(size_t)(cc * 8 + 2 * jj) * NSEQ];
        const float f1 = xp[(size_t)(cc * 8 + 2 * jj + 1) * NSEQ];
        pk[jj] = cvt_pk_bf16(f0, f1);
      }
      *(uint4*)&xs[l * 128 + ((c ^ (l & 15)) * 8)] = *(uint4*)pk;
    }
  }

  const float* W;
  float scale = 1.0f;
  if (w == 0)      { W = Wq; scale = 0.180336880111120429f; }  // log2e/8
  else if (w == 1) { W = Wk; }
  else if (w == 2) { W = Wv; }
  else             { W = Wv + 64 * DIN; }

  bf16x8 wf[4][4];
  #pragma unroll
  for (int ct = 0; ct < 4; ++ct) {
    const float* wr = W + (ct * 16 + li) * DIN + lg * 8;
    #pragma unroll
    for (int ks = 0; ks < 4; ++ks) {
      const float4 f0 = *(const float4*)(wr + 32 * ks);
      const float4 f1 = *(const float4*)(wr + 32 * ks + 4);
      u32x4v pk;
      pk[0] = cvt_pk_bf16(f0.x * scale, f0.y * scale);
      pk[1] = cvt_pk_bf16(f0.z * scale, f0.w * scale);
      pk[2] = cvt_pk_bf16(f1.x * scale, f1.y * scale);
      pk[3] = cvt_pk_bf16(f1.z * scale, f1.w * scale);
      wf[ct][ks] = __builtin_bit_cast(bf16x8, pk);
    }
  }

  __syncthreads();

  const f32x4 fz = {0.f, 0.f, 0.f, 0.f};
  #pragma unroll
  for (int nt = 0; nt < 4; ++nt) {
    const int n16 = n0 + nt * 16;
    bf16x8 xf[4];
    #pragma unroll
    for (int ks = 0; ks < 4; ++ks)
      xf[ks] = *(const bf16x8*)&xs[(nt * 16 + li) * 128 + (((lg + 4 * ks) ^ li) * 8)];
    #pragma unroll
    for (int ct = 0; ct < 4; ++ct) {
      f32x4 acc = fz;
      if (w < 2) {
        #pragma unroll
        for (int ks = 0; ks < 4; ++ks)
          acc = __builtin_amdgcn_mfma_f32_16x16x32_bf16(xf[ks], wf[ct][ks], acc, 0, 0, 0);
        u16* ob = (w == 0 ? Qb : Kb) + (size_t)b * NSEQ * DK;
        #pragma unroll
        for (int r = 0; r < 4; ++r)
          ob[(size_t)(n16 + lg * 4 + r) * DK + ct * 16 + li] =
              (u16)cvt_pk_bf16(acc[r], acc[r]);
      } else {
        #pragma unroll
        for (int ks = 0; ks < 4; ++ks)
          acc = __builtin_amdgcn_mfma_f32_16x16x32_bf16(wf[ct][ks], xf[ks], acc, 0, 0, 0);
        const int chb = (w == 3 ? 64 : 0) + ct * 16 + lg * 4;
        #pragma unroll
        for (int r = 0; r < 4; ++r)
          Vtb[((size_t)b * DVV + chb + r) * NSEQ + n16 + li] =
              (u16)cvt_pk_bf16(acc[r], acc[r]);
      }
    }
  }
}

// ------- fused flash attention: kv-split-4, Wq=64, private-LDS V via global_load_lds -------
// 512 blocks (b(8)=XCD x qg(64)) x 4 waves. Wave w owns kv quarter [w*1024,(w+1)*1024),
// KVBLK=32, and ALL 64 q rows (4 q-halves). V staged by async global_load_lds
// (per-lane global src, uniform LDS dest + lane*16) -> NO staging registers, NO
// ds_writes. No __syncthreads in the main loop (buffers are wave-private).
// vmcnt FIFO discipline: V(t) issued before K(t) in iter t-1; QK's auto-wait on
// kf(t) implies V(t) complete; explicit vmcnt(12)+sched_barrier before PV as the
// safety net (12 = this iter's 8 V + 4 K issues; exact for prologue too).
// K: register fragments gathered from L2. Fixed-max softmax (shift-invariant).
__global__ __launch_bounds__(256, 2) void attn(
    const u16* __restrict__ Qb, const u16* __restrict__ Kb,
    const u16* __restrict__ Vtb, const float* __restrict__ x,
    float* __restrict__ out) {
  __shared__ alignas(16) char lds[69632];  // main 4x16KB; epi 2x33792 + 1KB stats
  const int tid = threadIdx.x;
  const int w = tid >> 6, l = tid & 63;
  const int lg = l >> 4, li = l & 15;
  const int b = blockIdx.x & 7;
  const int qbase = (blockIdx.x >> 3) << 6;

  // Q B-fragments: qf[h][kc]: col q = qbase+16h+li, d-chunk kc*32 + lg*8
  bf16x8 qf[4][2];
  #pragma unroll
  for (int h = 0; h < 4; ++h) {
    const u16* qp = Qb + ((size_t)(b * NSEQ + qbase + h * 16 + li) * DK + lg * 8);
    qf[h][0] = *(const bf16x8*)qp;
    qf[h][1] = *(const bf16x8*)(qp + 32);
  }

  const f32x4 fzero = {0.f, 0.f, 0.f, 0.f};
  f32x4 oacc[4][8];
  #pragma unroll
  for (int h = 0; h < 4; ++h)
    #pragma unroll
    for (int dt = 0; dt < 8; ++dt) oacc[h][dt] = fzero;
  float lrow[4] = {0.f, 0.f, 0.f, 0.f};

  // K gather base (row-permutation folded): A-row li of QK tile jt holds actual
  // kv row 8*(li>>2) + 4*jt + (li&3) within the 32-row tile.
  const u16* kbase = Kb + ((size_t)b * NSEQ + 8 * (li >> 2) + (li & 3)) * DK + lg * 8;
  // V stage source: lane l, slot s reads V^T[s*16 + (l>>2)][t*32 + (l&3)*8 ..+7]
  const u16* vsrc = Vtb + ((size_t)b * DVV + (l >> 2)) * NSEQ + (l & 3) * 8;
  char* const mybuf = lds + w * 16384;   // two private 8KB tiles

  bf16x8 kf[2][2];
#define KLOAD(T) do {                                                         \
    const u16* kp_ = kbase + (size_t)(T) * 32 * DK;                           \
    _Pragma("unroll") for (int jt = 0; jt < 2; ++jt)                          \
      _Pragma("unroll") for (int kc = 0; kc < 2; ++kc)                        \
        kf[jt][kc] = *(const bf16x8*)(kp_ + jt * 4 * DK + kc * 32);           \
  } while (0)
// async-stage tile T into private buf B: dest slot s at s*1024 + lane*16
#define STAGEV(T, B) do {                                                     \
    char* vb_ = mybuf + (B) * 8192;                                           \
    _Pragma("unroll") for (int s = 0; s < 8; ++s)                             \
      GLDS16(vsrc + (size_t)s * 16 * NSEQ + (size_t)(T) * 32, vb_ + s * 1024); \
  } while (0)

  const int t0 = w * 32;                 // this wave's first kv tile
  KLOAD(t0);                             // K(t0) issued BEFORE V(t0)
  STAGEV(t0, 0);

  #pragma unroll 1
  for (int i = 0; i < 32; ++i) {
    const int t = t0 + i;
    const int cur = i & 1;
    if (i < 31) STAGEV(t + 1, cur ^ 1);  // async V for next tile (8 vmcnt ops)

    // ---- S^T = K Q^T + fixed-max softmax + in-lane P pack, per q-half ----
    bf16x8 pf[4];
    __builtin_amdgcn_s_setprio(1);
    #pragma unroll
    for (int h = 0; h < 4; ++h) {
      f32x4 a0 = __builtin_amdgcn_mfma_f32_16x16x32_bf16(kf[0][0], qf[h][0], fzero, 0, 0, 0);
      a0 = __builtin_amdgcn_mfma_f32_16x16x32_bf16(kf[0][1], qf[h][1], a0, 0, 0, 0);
      f32x4 a1 = __builtin_amdgcn_mfma_f32_16x16x32_bf16(kf[1][0], qf[h][0], fzero, 0, 0, 0);
      a1 = __builtin_amdgcn_mfma_f32_16x16x32_bf16(kf[1][1], qf[h][1], a1, 0, 0, 0);
      float p0 = __builtin_amdgcn_exp2f(a0[0]);
      float p1 = __builtin_amdgcn_exp2f(a0[1]);
      float p2 = __builtin_amdgcn_exp2f(a0[2]);
      float p3 = __builtin_amdgcn_exp2f(a0[3]);
      float p4 = __builtin_amdgcn_exp2f(a1[0]);
      float p5 = __builtin_amdgcn_exp2f(a1[1]);
      float p6 = __builtin_amdgcn_exp2f(a1[2]);
      float p7 = __builtin_amdgcn_exp2f(a1[3]);
      lrow[h] += ((p0 + p1) + (p2 + p3)) + ((p4 + p5) + (p6 + p7));
      u32x4v pk;
      pk[0] = cvt_pk_bf16(p0, p1);
      pk[1] = cvt_pk_bf16(p2, p3);
      pk[2] = cvt_pk_bf16(p4, p5);
      pk[3] = cvt_pk_bf16(p6, p7);
      pf[h] = __builtin_bit_cast(bf16x8, pk);
    }
    __builtin_amdgcn_s_setprio(0);

    if (i < 31) KLOAD(t + 1);            // K gather for next tile (kf now dead)

    // V(t) guaranteed complete once <=12 newest (this iter's 8V+4K) outstanding
    asm volatile("s_waitcnt vmcnt(12)" ::: "memory");
    __builtin_amdgcn_sched_barrier(0);

    // ---- O^T += V^T P  (V frags from private LDS, shared across 4 halves) ----
    const char* vb = mybuf + cur * 8192;
    __builtin_amdgcn_s_setprio(1);
    #pragma unroll
    for (int dt = 0; dt < 8; ++dt) {
      const bf16x8 vf = *(const bf16x8*)(vb + dt * 1024 + li * 64 + lg * 16);
      #pragma unroll
      for (int h = 0; h < 4; ++h)
        oacc[h][dt] = __builtin_amdgcn_mfma_f32_16x16x32_bf16(vf, pf[h], oacc[h][dt], 0, 0, 0);
    }
    __builtin_amdgcn_s_setprio(0);
  }

  // ---- epilogue: 4-partial merge tree (the only barriers) ----
  #pragma unroll
  for (int h = 0; h < 4; ++h) {          // reduce l over lg groups
    lrow[h] += __shfl_xor(lrow[h], 16, 64);
    lrow[h] += __shfl_xor(lrow[h], 32, 64);
  }
  float* const bufA = (float*)lds;                 // [128 dv][66] f32
  float* const bufB = (float*)(lds + 33792);       // [128 dv][66] f32
  float* const stats = (float*)(lds + 67584);      // [4 w][4 h][16 li]
#define DUMP(DST) do {                                                        \
    _Pragma("unroll") for (int h = 0; h < 4; ++h)                             \
      _Pragma("unroll") for (int dt = 0; dt < 8; ++dt)                        \
        _Pragma("unroll") for (int r = 0; r < 4; ++r)                         \
          (DST)[(dt * 16 + lg * 4 + r) * 66 + h * 16 + li] = oacc[h][dt][r];  \
  } while (0)
#define ADDF(SRC) do {                                                        \
    _Pragma("unroll") for (int h = 0; h < 4; ++h)                             \
      _Pragma("unroll") for (int dt = 0; dt < 8; ++dt)                        \
        _Pragma("unroll") for (int r = 0; r < 4; ++r)                         \
          oacc[h][dt][r] += (SRC)[(dt * 16 + lg * 4 + r) * 66 + h * 16 + li]; \
  } while (0)
#define SAVESTATS(WI) do {                                                    \
    if (lg == 0) {                                                            \
      for (int h = 0; h < 4; ++h) stats[(WI) * 64 + h * 16 + li] = lrow[h];   \
    }                                                                         \
  } while (0)
  __syncthreads();                        // V bufs dead; epilogue regions live
  if (w == 1) { DUMP(bufA); SAVESTATS(1); }
  if (w == 3) { DUMP(bufB); SAVESTATS(3); }
  __syncthreads();
  if (w == 0) ADDF(bufA);
  if (w == 2) {
    ADDF(bufB);
    #pragma unroll
    for (int h = 0; h < 4; ++h) lrow[h] += stats[3 * 64 + h * 16 + li];
  }
  __syncthreads();
  if (w == 2) { DUMP(bufA); SAVESTATS(2); }
  __syncthreads();
  if (w == 0) {
    ADDF(bufA);
    #pragma unroll
    for (int h = 0; h < 4; ++h) {
      const float ls = lrow[h] + stats[1 * 64 + h * 16 + li] + stats[2 * 64 + h * 16 + li];
      const float rl = 1.0f / ls;
      #pragma unroll
      for (int dt = 0; dt < 8; ++dt) {
        #pragma unroll
        for (int r = 0; r < 4; ++r) {
          const int dv = dt * 16 + lg * 4 + r;
          const size_t idx = ((size_t)b * DVV + dv) * NSEQ + qbase + h * 16 + li;
          out[idx] = oacc[h][dt][r] * rl + x[idx];
        }
      }
    }
  }
#undef KLOAD
#undef STAGEV
#undef DUMP
#undef ADDF
#undef SAVESTATS
}

extern "C" void kernel_launch(void* const* d_in, const int* in_sizes, int n_in,
                              void* d_out, int out_size, void* d_ws, size_t ws_size,
                              hipStream_t stream) {
  const float* x  = (const float*)d_in[0];
  const float* Wq = (const float*)d_in[1];
  const float* Wk = (const float*)d_in[2];
  const float* Wv = (const float*)d_in[3];
  float* out = (float*)d_out;

  u16* qws = (u16*)d_ws;                                   // [8][4096][64]
  u16* kws = qws + (size_t)NB * NSEQ * DK;                 // [8][4096][64]
  u16* vws = kws + (size_t)NB * NSEQ * DK;                 // [8][128][4096]

  proj<<<512, 256, 0, stream>>>(x, Wq, Wk, Wv, qws, kws, vws);
  attn<<<512, 256, 0, stream>>>(qws, kws, vws, x, out);
}

// Round 12
// 77.668 us; speedup vs baseline: 2.4644x; 1.0731x over previous
//
#include <hip/hip_runtime.h>
#include <hip/hip_bf16.h>
#include <stdint.h>

#define NB   8
#define NSEQ 4096
#define DIN  128
#define DK   64
#define DVV  128

typedef __bf16 bf16x8 __attribute__((ext_vector_type(8)));
typedef float f32x4 __attribute__((ext_vector_type(4)));
typedef unsigned int u32x4v __attribute__((ext_vector_type(4)));
typedef unsigned short u16;
typedef unsigned int u32;

__device__ __forceinline__ u32 cvt_pk_bf16(float lo, float hi) {
  u32 r;
  asm("v_cvt_pk_bf16_f32 %0, %1, %2" : "=v"(r) : "v"(lo), "v"(hi));
  return r;
}

// async global->LDS, 16B/lane; LDS dest = wave-uniform base + lane*16 (HW rule)
#define GLDS16(G, L)                                                          \
  __builtin_amdgcn_global_load_lds(                                           \
      (__attribute__((address_space(1))) void*)(G),                           \
      (__attribute__((address_space(3))) void*)(L), 16, 0, 0)

// ---------------- projection via MFMA, single-pass x ----------------
// Writes K and V in FRAGMENT-LINEAR tile layouts (exact lane order of attn's
// loads) so attn's per-iter global reads are fully coalesced 1KB bursts:
//   Kf[b][t(128)][jt(2)][kc(2)][lane(64)][8]  (4KB per 32-kv tile)
//   Vf[b][t(128)][slot s(8)][lane lp(64)][8]  (8KB per tile), where
//   lp = (dv&7) | ((kv>>3)<<3) | (((dv>>3)&1)<<5)  -> PV reads bank-conflict-free.
__global__ __launch_bounds__(256) void proj(
    const float* __restrict__ x, const float* __restrict__ Wq,
    const float* __restrict__ Wk, const float* __restrict__ Wv,
    u16* __restrict__ Qb, u16* __restrict__ Kf, u16* __restrict__ Vf) {
  __shared__ alignas(16) u16 xs[64 * 128];
  const int tid = threadIdx.x;
  const int w = tid >> 6, l = tid & 63;
  const int lg = l >> 4, li = l & 15;
  const int b = blockIdx.x & 7;
  const int n0 = (blockIdx.x >> 3) << 6;

  {
    const float* xp = x + ((size_t)b * DIN + w * 32) * NSEQ + n0 + l;
    #pragma unroll
    for (int cc = 0; cc < 4; ++cc) {
      const int c = w * 4 + cc;
      u32 pk[4];
      #pragma unroll
      for (int jj = 0; jj < 4; ++jj) {
        const float f0 = xp[(size_t)(cc * 8 + 2 * jj) * NSEQ];
        const float f1 = xp[(size_t)(cc * 8 + 2 * jj + 1) * NSEQ];
        pk[jj] = cvt_pk_bf16(f0, f1);
      }
      *(uint4*)&xs[l * 128 + ((c ^ (l & 15)) * 8)] = *(uint4*)pk;
    }
  }

  const float* W;
  float scale = 1.0f;
  if (w == 0)      { W = Wq; scale = 0.180336880111120429f; }  // log2e/8
  else if (w == 1) { W = Wk; }
  else if (w == 2) { W = Wv; }
  else             { W = Wv + 64 * DIN; }

  bf16x8 wf[4][4];
  #pragma unroll
  for (int ct = 0; ct < 4; ++ct) {
    const float* wr = W + (ct * 16 + li) * DIN + lg * 8;
    #pragma unroll
    for (int ks = 0; ks < 4; ++ks) {
      const float4 f0 = *(const float4*)(wr + 32 * ks);
      const float4 f1 = *(const float4*)(wr + 32 * ks + 4);
      u32x4v pk;
      pk[0] = cvt_pk_bf16(f0.x * scale, f0.y * scale);
      pk[1] = cvt_pk_bf16(f0.z * scale, f0.w * scale);
      pk[2] = cvt_pk_bf16(f1.x * scale, f1.y * scale);
      pk[3] = cvt_pk_bf16(f1.z * scale, f1.w * scale);
      wf[ct][ks] = __builtin_bit_cast(bf16x8, pk);
    }
  }

  __syncthreads();

  const f32x4 fz = {0.f, 0.f, 0.f, 0.f};
  #pragma unroll
  for (int nt = 0; nt < 4; ++nt) {
    const int n16 = n0 + nt * 16;
    bf16x8 xf[4];
    #pragma unroll
    for (int ks = 0; ks < 4; ++ks)
      xf[ks] = *(const bf16x8*)&xs[(nt * 16 + li) * 128 + (((lg + 4 * ks) ^ li) * 8)];
    #pragma unroll
    for (int ct = 0; ct < 4; ++ct) {
      f32x4 acc = fz;
      if (w < 2) {
        #pragma unroll
        for (int ks = 0; ks < 4; ++ks)
          acc = __builtin_amdgcn_mfma_f32_16x16x32_bf16(xf[ks], wf[ct][ks], acc, 0, 0, 0);
        if (w == 0) {
          u16* ob = Qb + (size_t)b * NSEQ * DK;
          #pragma unroll
          for (int r = 0; r < 4; ++r)
            ob[(size_t)(n16 + lg * 4 + r) * DK + ct * 16 + li] =
                (u16)cvt_pk_bf16(acc[r], acc[r]);
        } else {
          // K fragment-linear: element (n, d=ct*16+li)
          #pragma unroll
          for (int r = 0; r < 4; ++r) {
            const int n = n16 + lg * 4 + r;
            const int t = n >> 5, rowin = n & 31;
            const int jt = (rowin >> 2) & 1;
            const int lip = 4 * (rowin >> 3) + (rowin & 3);
            const int kc = ct >> 1;
            const int lgp = ((ct & 1) * 16 + li) >> 3;
            Kf[((size_t)(b * 128 + t)) * 2048 + (jt * 2 + kc) * 512 +
               (lgp * 16 + lip) * 8 + (li & 7)] = (u16)cvt_pk_bf16(acc[r], acc[r]);
          }
        }
      } else {
        #pragma unroll
        for (int ks = 0; ks < 4; ++ks)
          acc = __builtin_amdgcn_mfma_f32_16x16x32_bf16(wf[ct][ks], xf[ks], acc, 0, 0, 0);
        const int chb = (w == 3 ? 64 : 0) + ct * 16 + lg * 4;
        // V fragment-linear: element (dv=chb+r, n=n16+li)
        #pragma unroll
        for (int r = 0; r < 4; ++r) {
          const int dv = chb + r;
          const int n = n16 + li;
          const int t = n >> 5, kv = n & 31;
          const int s = dv >> 4;
          const int lp = (dv & 7) | ((kv >> 3) << 3) | (((dv >> 3) & 1) << 5);
          Vf[((size_t)(b * 128 + t)) * 4096 + s * 512 + lp * 8 + (kv & 7)] =
              (u16)cvt_pk_bf16(acc[r], acc[r]);
        }
      }
    }
  }
}

// ------- fused flash attention: kv-split-4, Wq=64, fragment-linear K/V streams -------
// 512 blocks (b(8)=XCD x qg(64)) x 4 waves. Wave w owns kv quarter, KVBLK=32,
// all 64 q rows. K: 4 coalesced 1KB register loads per tile (fragment-linear).
// V: 8 coalesced 1KB global_load_lds per tile into private double-buffered LDS;
// chunk order chosen so PV b128 reads are bank-exact to contiguous (conflict-free).
// No __syncthreads in main loop. vmcnt(12)+sched_barrier before PV (safety net;
// no-op in steady state since QK's kf wait already drains V(t)).
__global__ __launch_bounds__(256, 2) void attn(
    const u16* __restrict__ Qb, const u16* __restrict__ Kf,
    const u16* __restrict__ Vf, const float* __restrict__ x,
    float* __restrict__ out) {
  __shared__ alignas(16) char lds[69632];  // main 4x16KB; epi 2x34304 + 1KB stats
  const int tid = threadIdx.x;
  const int w = tid >> 6, l = tid & 63;
  const int lg = l >> 4, li = l & 15;
  const int b = blockIdx.x & 7;
  const int qbase = (blockIdx.x >> 3) << 6;

  // Q B-fragments: qf[h][kc]: col q = qbase+16h+li, d-chunk kc*32 + lg*8
  bf16x8 qf[4][2];
  #pragma unroll
  for (int h = 0; h < 4; ++h) {
    const u16* qp = Qb + ((size_t)(b * NSEQ + qbase + h * 16 + li) * DK + lg * 8);
    qf[h][0] = *(const bf16x8*)qp;
    qf[h][1] = *(const bf16x8*)(qp + 32);
  }

  const f32x4 fzero = {0.f, 0.f, 0.f, 0.f};
  f32x4 oacc[4][8];
  #pragma unroll
  for (int h = 0; h < 4; ++h)
    #pragma unroll
    for (int dt = 0; dt < 8; ++dt) oacc[h][dt] = fzero;
  float lrow[4] = {0.f, 0.f, 0.f, 0.f};

  const u16* kbase = Kf + (size_t)b * 128 * 2048 + l * 8;   // lane-linear
  const u16* vbase = Vf + (size_t)b * 128 * 4096 + l * 8;   // lane-linear
  char* const mybuf = lds + w * 16384;   // two private 8KB tiles
  // PV read chunk byte offset (conflict-free order; matches Vf's lp encoding)
  const int vq = (((li & 7) | (lg << 3) | ((li >> 3) << 5)) << 4);

  bf16x8 kf[2][2];
#define KLOAD(T) do {                                                         \
    const u16* kp_ = kbase + (size_t)(T) * 2048;                              \
    _Pragma("unroll") for (int jt = 0; jt < 2; ++jt)                          \
      _Pragma("unroll") for (int kc = 0; kc < 2; ++kc)                        \
        kf[jt][kc] = *(const bf16x8*)(kp_ + (jt * 2 + kc) * 512);             \
  } while (0)
#define STAGEV(T, B) do {                                                     \
    char* vb_ = mybuf + (B) * 8192;                                           \
    const u16* vp_ = vbase + (size_t)(T) * 4096;                              \
    _Pragma("unroll") for (int s = 0; s < 8; ++s)                             \
      GLDS16(vp_ + s * 512, vb_ + s * 1024);                                  \
  } while (0)

  const int t0 = w * 32;                 // this wave's first kv tile
  STAGEV(t0, 0);                         // V(t0) issued BEFORE K(t0)
  KLOAD(t0);

  #pragma unroll 1
  for (int i = 0; i < 32; ++i) {
    const int t = t0 + i;
    const int cur = i & 1;
    if (i < 31) STAGEV(t + 1, cur ^ 1);  // async V for next tile

    // ---- S^T = K Q^T + fixed-max softmax + in-lane P pack, per q-half ----
    bf16x8 pf[4];
    __builtin_amdgcn_s_setprio(1);
    #pragma unroll
    for (int h = 0; h < 4; ++h) {
      f32x4 a0 = __builtin_amdgcn_mfma_f32_16x16x32_bf16(kf[0][0], qf[h][0], fzero, 0, 0, 0);
      a0 = __builtin_amdgcn_mfma_f32_16x16x32_bf16(kf[0][1], qf[h][1], a0, 0, 0, 0);
      f32x4 a1 = __builtin_amdgcn_mfma_f32_16x16x32_bf16(kf[1][0], qf[h][0], fzero, 0, 0, 0);
      a1 = __builtin_amdgcn_mfma_f32_16x16x32_bf16(kf[1][1], qf[h][1], a1, 0, 0, 0);
      float p0 = __builtin_amdgcn_exp2f(a0[0]);
      float p1 = __builtin_amdgcn_exp2f(a0[1]);
      float p2 = __builtin_amdgcn_exp2f(a0[2]);
      float p3 = __builtin_amdgcn_exp2f(a0[3]);
      float p4 = __builtin_amdgcn_exp2f(a1[0]);
      float p5 = __builtin_amdgcn_exp2f(a1[1]);
      float p6 = __builtin_amdgcn_exp2f(a1[2]);
      float p7 = __builtin_amdgcn_exp2f(a1[3]);
      lrow[h] += ((p0 + p1) + (p2 + p3)) + ((p4 + p5) + (p6 + p7));
      u32x4v pk;
      pk[0] = cvt_pk_bf16(p0, p1);
      pk[1] = cvt_pk_bf16(p2, p3);
      pk[2] = cvt_pk_bf16(p4, p5);
      pk[3] = cvt_pk_bf16(p6, p7);
      pf[h] = __builtin_bit_cast(bf16x8, pk);
    }
    __builtin_amdgcn_s_setprio(0);

    if (i < 31) KLOAD(t + 1);            // coalesced K for next tile (kf dead)

    // V(t) complete once <=12 newest (this iter's 8 V + 4 K) outstanding
    asm volatile("s_waitcnt vmcnt(12)" ::: "memory");
    __builtin_amdgcn_sched_barrier(0);

    // ---- O^T += V^T P  (V frags from private LDS, shared across 4 halves) ----
    const char* vb = mybuf + cur * 8192;
    __builtin_amdgcn_s_setprio(1);
    #pragma unroll
    for (int dt = 0; dt < 8; ++dt) {
      const bf16x8 vf = *(const bf16x8*)(vb + dt * 1024 + vq);
      #pragma unroll
      for (int h = 0; h < 4; ++h)
        oacc[h][dt] = __builtin_amdgcn_mfma_f32_16x16x32_bf16(vf, pf[h], oacc[h][dt], 0, 0, 0);
    }
    __builtin_amdgcn_s_setprio(0);
  }

  // ---- epilogue: 4-partial merge tree (the only barriers) ----
  #pragma unroll
  for (int h = 0; h < 4; ++h) {          // reduce l over lg groups
    lrow[h] += __shfl_xor(lrow[h], 16, 64);
    lrow[h] += __shfl_xor(lrow[h], 32, 64);
  }
  float* const bufA = (float*)lds;                 // [128 dv][67] f32
  float* const bufB = (float*)(lds + 34304);       // [128 dv][67] f32
  float* const stats = (float*)(lds + 68608);      // [4 w][4 h][16 li]
#define DUMP(DST) do {                                                        \
    _Pragma("unroll") for (int h = 0; h < 4; ++h)                             \
      _Pragma("unroll") for (int dt = 0; dt < 8; ++dt)                        \
        _Pragma("unroll") for (int r = 0; r < 4; ++r)                         \
          (DST)[(dt * 16 + lg * 4 + r) * 67 + h * 16 + li] = oacc[h][dt][r];  \
  } while (0)
#define ADDF(SRC) do {                                                        \
    _Pragma("unroll") for (int h = 0; h < 4; ++h)                             \
      _Pragma("unroll") for (int dt = 0; dt < 8; ++dt)                        \
        _Pragma("unroll") for (int r = 0; r < 4; ++r)                         \
          oacc[h][dt][r] += (SRC)[(dt * 16 + lg * 4 + r) * 67 + h * 16 + li]; \
  } while (0)
#define SAVESTATS(WI) do {                                                    \
    if (lg == 0) {                                                            \
      for (int h = 0; h < 4; ++h) stats[(WI) * 64 + h * 16 + li] = lrow[h];   \
    }                                                                         \
  } while (0)
  __syncthreads();                        // V bufs dead; epilogue regions live
  if (w == 1) { DUMP(bufA); SAVESTATS(1); }
  if (w == 3) { DUMP(bufB); SAVESTATS(3); }
  __syncthreads();
  if (w == 0) ADDF(bufA);
  if (w == 2) {
    ADDF(bufB);
    #pragma unroll
    for (int h = 0; h < 4; ++h) lrow[h] += stats[3 * 64 + h * 16 + li];
  }
  __syncthreads();
  if (w == 2) { DUMP(bufA); SAVESTATS(2); }
  __syncthreads();
  if (w == 0) {
    ADDF(bufA);
    #pragma unroll
    for (int h = 0; h < 4; ++h) {
      const float ls = lrow[h] + stats[1 * 64 + h * 16 + li] + stats[2 * 64 + h * 16 + li];
      const float rl = 1.0f / ls;
      #pragma unroll
      for (int dt = 0; dt < 8; ++dt) {
        #pragma unroll
        for (int r = 0; r < 4; ++r) {
          const int dv = dt * 16 + lg * 4 + r;
          const size_t idx = ((size_t)b * DVV + dv) * NSEQ + qbase + h * 16 + li;
          out[idx] = oacc[h][dt][r] * rl + x[idx];
        }
      }
    }
  }
#undef KLOAD
#undef STAGEV
#undef DUMP
#undef ADDF
#undef SAVESTATS
}

extern "C" void kernel_launch(void* const* d_in, const int* in_sizes, int n_in,
                              void* d_out, int out_size, void* d_ws, size_t ws_size,
                              hipStream_t stream) {
  const float* x  = (const float*)d_in[0];
  const float* Wq = (const float*)d_in[1];
  const float* Wk = (const float*)d_in[2];
  const float* Wv = (const float*)d_in[3];
  float* out = (float*)d_out;

  u16* qws = (u16*)d_ws;                                   // [8][4096][64]   4MB
  u16* kws = qws + (size_t)NB * NSEQ * DK;                 // Kf frag-linear  4MB
  u16* vws = kws + (size_t)NB * NSEQ * DK;                 // Vf frag-linear  8MB

  proj<<<512, 256, 0, stream>>>(x, Wq, Wk, Wv, qws, kws, vws);
  attn<<<512, 256, 0, stream>>>(qws, kws, vws, x, out);
}

// Round 13
// 75.963 us; speedup vs baseline: 2.5197x; 1.0224x over previous
//
#include <hip/hip_runtime.h>
#include <hip/hip_bf16.h>
#include <stdint.h>

#define NB   8
#define NSEQ 4096
#define DIN  128
#define DK   64
#define DVV  128

typedef __bf16 bf16x8 __attribute__((ext_vector_type(8)));
typedef float f32x4 __attribute__((ext_vector_type(4)));
typedef float f32x2 __attribute__((ext_vector_type(2)));
typedef unsigned int u32x4v __attribute__((ext_vector_type(4)));
typedef unsigned short u16;
typedef unsigned int u32;

__device__ __forceinline__ u32 cvt_pk_bf16(float lo, float hi) {
  u32 r;
  asm("v_cvt_pk_bf16_f32 %0, %1, %2" : "=v"(r) : "v"(lo), "v"(hi));
  return r;
}

// async global->LDS, 16B/lane; LDS dest = wave-uniform base + lane*16 (HW rule)
#define GLDS16(G, L)                                                          \
  __builtin_amdgcn_global_load_lds(                                           \
      (__attribute__((address_space(1))) void*)(G),                           \
      (__attribute__((address_space(3))) void*)(L), 16, 0, 0)

// ---------------- projection via MFMA, single-pass x (unchanged) ----------------
// Fragment-linear K/V workspace layouts (attn's exact lane order):
//   Kf[b][t(128)][jt*2+kc][lane][8], Vf[b][t(128)][slot][lp][8],
//   lp = (dv&7) | ((kv>>3)<<3) | (((dv>>3)&1)<<5).
__global__ __launch_bounds__(256) void proj(
    const float* __restrict__ x, const float* __restrict__ Wq,
    const float* __restrict__ Wk, const float* __restrict__ Wv,
    u16* __restrict__ Qb, u16* __restrict__ Kf, u16* __restrict__ Vf) {
  __shared__ alignas(16) u16 xs[64 * 128];
  const int tid = threadIdx.x;
  const int w = tid >> 6, l = tid & 63;
  const int lg = l >> 4, li = l & 15;
  const int b = blockIdx.x & 7;
  const int n0 = (blockIdx.x >> 3) << 6;

  {
    const float* xp = x + ((size_t)b * DIN + w * 32) * NSEQ + n0 + l;
    #pragma unroll
    for (int cc = 0; cc < 4; ++cc) {
      const int c = w * 4 + cc;
      u32 pk[4];
      #pragma unroll
      for (int jj = 0; jj < 4; ++jj) {
        const float f0 = xp[(size_t)(cc * 8 + 2 * jj) * NSEQ];
        const float f1 = xp[(size_t)(cc * 8 + 2 * jj + 1) * NSEQ];
        pk[jj] = cvt_pk_bf16(f0, f1);
      }
      *(uint4*)&xs[l * 128 + ((c ^ (l & 15)) * 8)] = *(uint4*)pk;
    }
  }

  const float* W;
  float scale = 1.0f;
  if (w == 0)      { W = Wq; scale = 0.180336880111120429f; }  // log2e/8
  else if (w == 1) { W = Wk; }
  else if (w == 2) { W = Wv; }
  else             { W = Wv + 64 * DIN; }

  bf16x8 wf[4][4];
  #pragma unroll
  for (int ct = 0; ct < 4; ++ct) {
    const float* wr = W + (ct * 16 + li) * DIN + lg * 8;
    #pragma unroll
    for (int ks = 0; ks < 4; ++ks) {
      const float4 f0 = *(const float4*)(wr + 32 * ks);
      const float4 f1 = *(const float4*)(wr + 32 * ks + 4);
      u32x4v pk;
      pk[0] = cvt_pk_bf16(f0.x * scale, f0.y * scale);
      pk[1] = cvt_pk_bf16(f0.z * scale, f0.w * scale);
      pk[2] = cvt_pk_bf16(f1.x * scale, f1.y * scale);
      pk[3] = cvt_pk_bf16(f1.z * scale, f1.w * scale);
      wf[ct][ks] = __builtin_bit_cast(bf16x8, pk);
    }
  }

  __syncthreads();

  const f32x4 fz = {0.f, 0.f, 0.f, 0.f};
  #pragma unroll
  for (int nt = 0; nt < 4; ++nt) {
    const int n16 = n0 + nt * 16;
    bf16x8 xf[4];
    #pragma unroll
    for (int ks = 0; ks < 4; ++ks)
      xf[ks] = *(const bf16x8*)&xs[(nt * 16 + li) * 128 + (((lg + 4 * ks) ^ li) * 8)];
    #pragma unroll
    for (int ct = 0; ct < 4; ++ct) {
      f32x4 acc = fz;
      if (w < 2) {
        #pragma unroll
        for (int ks = 0; ks < 4; ++ks)
          acc = __builtin_amdgcn_mfma_f32_16x16x32_bf16(xf[ks], wf[ct][ks], acc, 0, 0, 0);
        if (w == 0) {
          u16* ob = Qb + (size_t)b * NSEQ * DK;
          #pragma unroll
          for (int r = 0; r < 4; ++r)
            ob[(size_t)(n16 + lg * 4 + r) * DK + ct * 16 + li] =
                (u16)cvt_pk_bf16(acc[r], acc[r]);
        } else {
          #pragma unroll
          for (int r = 0; r < 4; ++r) {
            const int n = n16 + lg * 4 + r;
            const int t = n >> 5, rowin = n & 31;
            const int jt = (rowin >> 2) & 1;
            const int lip = 4 * (rowin >> 3) + (rowin & 3);
            const int kc = ct >> 1;
            const int lgp = ((ct & 1) * 16 + li) >> 3;
            Kf[((size_t)(b * 128 + t)) * 2048 + (jt * 2 + kc) * 512 +
               (lgp * 16 + lip) * 8 + (li & 7)] = (u16)cvt_pk_bf16(acc[r], acc[r]);
          }
        }
      } else {
        #pragma unroll
        for (int ks = 0; ks < 4; ++ks)
          acc = __builtin_amdgcn_mfma_f32_16x16x32_bf16(wf[ct][ks], xf[ks], acc, 0, 0, 0);
        const int chb = (w == 3 ? 64 : 0) + ct * 16 + lg * 4;
        #pragma unroll
        for (int r = 0; r < 4; ++r) {
          const int dv = chb + r;
          const int n = n16 + li;
          const int t = n >> 5, kv = n & 31;
          const int s = dv >> 4;
          const int lp = (dv & 7) | ((kv >> 3) << 3) | (((dv >> 3) & 1) << 5);
          Vf[((size_t)(b * 128 + t)) * 4096 + s * 512 + lp * 8 + (kv & 7)] =
              (u16)cvt_pk_bf16(acc[r], acc[r]);
        }
      }
    }
  }
}

// ------- fused flash attention: kv-split-4, Wq=64, branch-free pipelined body -------
// 512 blocks x 4 waves, wave-private kv quarter, KVBLK=32, no main-loop barrier.
// Round-13 changes: sched_barrier removed (memory-clobber vmcnt(12) only — it is
// self-correcting: forces outstanding<=12 = {V(t+1),K(t+1)}, draining V(t) no
// matter where the scheduler puts the MFMAs); last iter peeled -> branch-free
// body; unroll 2 so QK(t+1) can hoist under SM/PV(t) (kf reused in place, no new
// buffers); KLOAD before softmax (500cyc L2 slack); packed f32x2 lrow sums.
__global__ __launch_bounds__(256, 2) void attn(
    const u16* __restrict__ Qb, const u16* __restrict__ Kf,
    const u16* __restrict__ Vf, const float* __restrict__ x,
    float* __restrict__ out) {
  __shared__ alignas(16) char lds[69632];
  const int tid = threadIdx.x;
  const int w = tid >> 6, l = tid & 63;
  const int lg = l >> 4, li = l & 15;
  const int b = blockIdx.x & 7;
  const int qbase = (blockIdx.x >> 3) << 6;

  bf16x8 qf[4][2];
  #pragma unroll
  for (int h = 0; h < 4; ++h) {
    const u16* qp = Qb + ((size_t)(b * NSEQ + qbase + h * 16 + li) * DK + lg * 8);
    qf[h][0] = *(const bf16x8*)qp;
    qf[h][1] = *(const bf16x8*)(qp + 32);
  }

  const f32x4 fzero = {0.f, 0.f, 0.f, 0.f};
  const f32x2 fz2 = {0.f, 0.f};
  f32x4 oacc[4][8];
  #pragma unroll
  for (int h = 0; h < 4; ++h)
    #pragma unroll
    for (int dt = 0; dt < 8; ++dt) oacc[h][dt] = fzero;
  f32x2 lrow2[4] = {fz2, fz2, fz2, fz2};

  const u16* kbase = Kf + (size_t)b * 128 * 2048 + l * 8;   // lane-linear
  const u16* vbase = Vf + (size_t)b * 128 * 4096 + l * 8;   // lane-linear
  char* const mybuf = lds + w * 16384;   // two private 8KB tiles
  const int vq = (((li & 7) | (lg << 3) | ((li >> 3) << 5)) << 4);

  bf16x8 kf[2][2];
#define KLOAD(T) do {                                                         \
    const u16* kp_ = kbase + (size_t)(T) * 2048;                              \
    _Pragma("unroll") for (int jt = 0; jt < 2; ++jt)                          \
      _Pragma("unroll") for (int kc = 0; kc < 2; ++kc)                        \
        kf[jt][kc] = *(const bf16x8*)(kp_ + (jt * 2 + kc) * 512);             \
  } while (0)
#define STAGEV(T, B) do {                                                     \
    char* vb_ = mybuf + (B) * 8192;                                           \
    const u16* vp_ = vbase + (size_t)(T) * 4096;                              \
    _Pragma("unroll") for (int s = 0; s < 8; ++s)                             \
      GLDS16(vp_ + s * 512, vb_ + s * 1024);                                  \
  } while (0)
// one iteration body; PREFETCH=1 stages/loads tile T+1
#define BODY(T, CUR, PREFETCH) do {                                           \
    if (PREFETCH) STAGEV((T) + 1, (CUR) ^ 1);                                 \
    bf16x8 pf[4];                                                             \
    __builtin_amdgcn_s_setprio(1);                                            \
    f32x4 sa[4], sb[4];                                                       \
    _Pragma("unroll") for (int h = 0; h < 4; ++h) {                           \
      sa[h] = __builtin_amdgcn_mfma_f32_16x16x32_bf16(kf[0][0], qf[h][0], fzero, 0, 0, 0); \
      sa[h] = __builtin_amdgcn_mfma_f32_16x16x32_bf16(kf[0][1], qf[h][1], sa[h], 0, 0, 0); \
      sb[h] = __builtin_amdgcn_mfma_f32_16x16x32_bf16(kf[1][0], qf[h][0], fzero, 0, 0, 0); \
      sb[h] = __builtin_amdgcn_mfma_f32_16x16x32_bf16(kf[1][1], qf[h][1], sb[h], 0, 0, 0); \
    }                                                                         \
    __builtin_amdgcn_s_setprio(0);                                            \
    if (PREFETCH) KLOAD((T) + 1);                                             \
    _Pragma("unroll") for (int h = 0; h < 4; ++h) {                           \
      const float p0 = __builtin_amdgcn_exp2f(sa[h][0]);                      \
      const float p1 = __builtin_amdgcn_exp2f(sa[h][1]);                      \
      const float p2 = __builtin_amdgcn_exp2f(sa[h][2]);                      \
      const float p3 = __builtin_amdgcn_exp2f(sa[h][3]);                      \
      const float p4 = __builtin_amdgcn_exp2f(sb[h][0]);                      \
      const float p5 = __builtin_amdgcn_exp2f(sb[h][1]);                      \
      const float p6 = __builtin_amdgcn_exp2f(sb[h][2]);                      \
      const float p7 = __builtin_amdgcn_exp2f(sb[h][3]);                      \
      f32x2 e0 = {p0, p1}, e1 = {p2, p3}, e2 = {p4, p5}, e3 = {p6, p7};       \
      lrow2[h] += (e0 + e1) + (e2 + e3);       /* v_pk_add_f32 */             \
      u32x4v pk;                                                              \
      pk[0] = cvt_pk_bf16(p0, p1);                                            \
      pk[1] = cvt_pk_bf16(p2, p3);                                            \
      pk[2] = cvt_pk_bf16(p4, p5);                                            \
      pk[3] = cvt_pk_bf16(p6, p7);                                            \
      pf[h] = __builtin_bit_cast(bf16x8, pk);                                 \
    }                                                                         \
    asm volatile("s_waitcnt vmcnt(12)" ::: "memory");                         \
    const char* vb = mybuf + (CUR) * 8192;                                    \
    __builtin_amdgcn_s_setprio(1);                                            \
    _Pragma("unroll") for (int dt = 0; dt < 8; ++dt) {                        \
      const bf16x8 vf = *(const bf16x8*)(vb + dt * 1024 + vq);                \
      _Pragma("unroll") for (int h = 0; h < 4; ++h)                           \
        oacc[h][dt] = __builtin_amdgcn_mfma_f32_16x16x32_bf16(vf, pf[h], oacc[h][dt], 0, 0, 0); \
    }                                                                         \
    __builtin_amdgcn_s_setprio(0);                                            \
  } while (0)

  const int t0 = w * 32;                 // this wave's first kv tile
  STAGEV(t0, 0);                         // V(t) always issued BEFORE K(t)
  KLOAD(t0);

  #pragma unroll 2
  for (int i = 0; i < 31; ++i) {         // branch-free pipelined body
    BODY(t0 + i, i & 1, 1);
  }
  BODY(t0 + 31, 1, 0);                   // peeled final iteration (31&1 = 1)

  // ---- epilogue: 4-partial merge tree (the only barriers) ----
  float lrow[4];
  #pragma unroll
  for (int h = 0; h < 4; ++h) {
    float ls = lrow2[h].x + lrow2[h].y;
    ls += __shfl_xor(ls, 16, 64);
    ls += __shfl_xor(ls, 32, 64);
    lrow[h] = ls;
  }
  float* const bufA = (float*)lds;                 // [128 dv][67] f32
  float* const bufB = (float*)(lds + 34304);       // [128 dv][67] f32
  float* const stats = (float*)(lds + 68608);      // [4 w][4 h][16 li]
#define DUMP(DST) do {                                                        \
    _Pragma("unroll") for (int h = 0; h < 4; ++h)                             \
      _Pragma("unroll") for (int dt = 0; dt < 8; ++dt)                        \
        _Pragma("unroll") for (int r = 0; r < 4; ++r)                         \
          (DST)[(dt * 16 + lg * 4 + r) * 67 + h * 16 + li] = oacc[h][dt][r];  \
  } while (0)
#define ADDF(SRC) do {                                                        \
    _Pragma("unroll") for (int h = 0; h < 4; ++h)                             \
      _Pragma("unroll") for (int dt = 0; dt < 8; ++dt)                        \
        _Pragma("unroll") for (int r = 0; r < 4; ++r)                         \
          oacc[h][dt][r] += (SRC)[(dt * 16 + lg * 4 + r) * 67 + h * 16 + li]; \
  } while (0)
#define SAVESTATS(WI) do {                                                    \
    if (lg == 0) {                                                            \
      for (int h = 0; h < 4; ++h) stats[(WI) * 64 + h * 16 + li] = lrow[h];   \
    }                                                                         \
  } while (0)
  __syncthreads();                        // V bufs dead; epilogue regions live
  if (w == 1) { DUMP(bufA); SAVESTATS(1); }
  if (w == 3) { DUMP(bufB); SAVESTATS(3); }
  __syncthreads();
  if (w == 0) ADDF(bufA);
  if (w == 2) {
    ADDF(bufB);
    #pragma unroll
    for (int h = 0; h < 4; ++h) lrow[h] += stats[3 * 64 + h * 16 + li];
  }
  __syncthreads();
  if (w == 2) { DUMP(bufA); SAVESTATS(2); }
  __syncthreads();
  if (w == 0) {
    ADDF(bufA);
    #pragma unroll
    for (int h = 0; h < 4; ++h) {
      const float ls = lrow[h] + stats[1 * 64 + h * 16 + li] + stats[2 * 64 + h * 16 + li];
      const float rl = 1.0f / ls;
      #pragma unroll
      for (int dt = 0; dt < 8; ++dt) {
        #pragma unroll
        for (int r = 0; r < 4; ++r) {
          const int dv = dt * 16 + lg * 4 + r;
          const size_t idx = ((size_t)b * DVV + dv) * NSEQ + qbase + h * 16 + li;
          out[idx] = oacc[h][dt][r] * rl + x[idx];
        }
      }
    }
  }
#undef KLOAD
#undef STAGEV
#undef BODY
#undef DUMP
#undef ADDF
#undef SAVESTATS
}

extern "C" void kernel_launch(void* const* d_in, const int* in_sizes, int n_in,
                              void* d_out, int out_size, void* d_ws, size_t ws_size,
                              hipStream_t stream) {
  const float* x  = (const float*)d_in[0];
  const float* Wq = (const float*)d_in[1];
  const float* Wk = (const float*)d_in[2];
  const float* Wv = (const float*)d_in[3];
  float* out = (float*)d_out;

  u16* qws = (u16*)d_ws;                                   // [8][4096][64]   4MB
  u16* kws = qws + (size_t)NB * NSEQ * DK;                 // Kf frag-linear  4MB
  u16* vws = kws + (size_t)NB * NSEQ * DK;                 // Vf frag-linear  8MB

  proj<<<512, 256, 0, stream>>>(x, Wq, Wk, Wv, qws, kws, vws);
  attn<<<512, 256, 0, stream>>>(qws, kws, vws, x, out);
}